// Round 7
// baseline (87.867 us; speedup 1.0000x reference)
//
#include <hip/hip_runtime.h>
#include <hip/hip_bf16.h>

// Problem constants (from setup_inputs): bs=16, nq=64, ngt=32, D=4096, ncls=33
#define BS   16
#define NQ   64
#define NGT  32
#define DIM  4096
#define NCLS 33

#define QT      8               // heat rows per block
#define NCHUNK  8               // D split
#define CHUNK   (DIM / NCHUNK)  // 512

// ---------------------------------------------------------------------------
// MEASUREMENT ROUND: kernels are byte-identical to round 5 (41.5 us known-good).
// kernel_launch runs lsap_kernel THREE times (idempotent) to isolate its
// duration: dur = C + 3L + ov  =>  L = (dur - 41.5)/2 - lambda.
// ---------------------------------------------------------------------------

// ---------------------------------------------------------------------------
// Kernel 1: partial cost  Cp[b][q][g][c] = sum_{d in chunk c} |heat[b,q,d]-gt[b,g,d]|
// ---------------------------------------------------------------------------
__global__ __launch_bounds__(256) void cost_kernel(
    const float* __restrict__ heat, const float* __restrict__ gt,
    float* __restrict__ Cp)
{
    __shared__ float hrow[QT][CHUNK];   // 16 KB
    const int bid  = blockIdx.x;        // 16*8*8 = 1024 blocks
    const int b    = bid & 15;
    const int rest = bid >> 4;          // 0..63
    const int qt   = rest & (NQ / QT - 1);  // 0..7
    const int c    = rest >> 3;         // 0..7
    const int q0   = qt * QT;

    const float* hbase = heat + ((size_t)(b * NQ + q0)) * DIM + c * CHUNK;
    for (int i = threadIdx.x; i < QT * CHUNK / 4; i += 256) {
        int r = i >> 7;        // / (CHUNK/4 = 128)
        int k = i & 127;
        ((float4*)hrow[r])[k] = ((const float4*)(hbase + (size_t)r * DIM))[k];
    }
    __syncthreads();

    const int wave = threadIdx.x >> 6;
    const int lane = threadIdx.x & 63;
    const int g0 = wave * 8;
    const float* gbase = gt + ((size_t)(b * NGT + g0)) * DIM + c * CHUNK;

    float acc[8][QT];
    #pragma unroll
    for (int g = 0; g < 8; ++g)
        #pragma unroll
        for (int q = 0; q < QT; ++q) acc[g][q] = 0.f;

    for (int i = lane; i < CHUNK / 4; i += 64) {   // 2 iterations
        float4 hv[QT];
        #pragma unroll
        for (int q = 0; q < QT; ++q) hv[q] = ((float4*)hrow[q])[i];
        #pragma unroll
        for (int g = 0; g < 8; ++g) {
            float4 gv = ((const float4*)(gbase + (size_t)g * DIM))[i];
            #pragma unroll
            for (int q = 0; q < QT; ++q) {
                acc[g][q] += fabsf(hv[q].x - gv.x) + fabsf(hv[q].y - gv.y) +
                             fabsf(hv[q].z - gv.z) + fabsf(hv[q].w - gv.w);
            }
        }
    }

    // 64-value butterfly: after 6 stages lane l holds total of value index l
    float r[64];
    #pragma unroll
    for (int k = 0; k < 64; ++k) r[k] = acc[k >> 3][k & 7];
    #pragma unroll
    for (int n = 64, m = 1; n > 1; n >>= 1, m <<= 1) {
        #pragma unroll
        for (int k = 0; k < 32; ++k) {
            if (k < n / 2) {
                float a  = r[2 * k], bb = r[2 * k + 1];
                bool  hi = (lane & m) != 0;
                float keep = hi ? bb : a;
                float send = hi ? a : bb;
                r[k] = keep + __shfl_xor(send, m);
            }
        }
    }
    {
        int gl = lane >> 3, ql = lane & 7;
        Cp[(((size_t)(b * NQ + (q0 + ql))) * NGT + (g0 + gl)) * NCHUNK + c] = r[0];
    }
}

// ---------------------------------------------------------------------------
// Helpers: DPP-based min (VALU pipe) and readlane.
// ---------------------------------------------------------------------------
__device__ __forceinline__ float dppmin(float x, const int ctrl) {
    int t;
    switch (ctrl) {   // ctrl must be a literal for the builtin
        case 0xB1:  t = __builtin_amdgcn_update_dpp(0, __float_as_int(x), 0xB1,  0xf, 0xf, true); break;
        case 0x4E:  t = __builtin_amdgcn_update_dpp(0, __float_as_int(x), 0x4E,  0xf, 0xf, true); break;
        case 0x141: t = __builtin_amdgcn_update_dpp(0, __float_as_int(x), 0x141, 0xf, 0xf, true); break;
        default:    t = __builtin_amdgcn_update_dpp(0, __float_as_int(x), 0x140, 0xf, 0xf, true); break;
    }
    return fminf(x, __int_as_float(t));
}
__device__ __forceinline__ float rdlane_f(float x, int l) {
    return __int_as_float(__builtin_amdgcn_readlane(__float_as_int(x), l));
}

// ---------------------------------------------------------------------------
// Kernel 2: exact rectangular LSAP (Jonker-Volgenant), one block per batch.
// (round-5 version: LDS cost matrix in the solver loop; sel32 reverted)
// ---------------------------------------------------------------------------
__global__ __launch_bounds__(256) void lsap_kernel(
    const float* __restrict__ Cp, const float* __restrict__ prob,
    const int* __restrict__ label, int* __restrict__ out)
{
    __shared__ float cost[NGT * NQ];
    const int b = blockIdx.x;
    const int tid = threadIdx.x;

    // 2048 entries / 256 threads = 8 iterations; writes conflict-free.
    for (int idx = tid; idx < NQ * NGT; idx += 256) {
        int q = idx & 63;
        int g = idx >> 6;
        const float* p = &Cp[(((size_t)(b * NQ + q)) * NGT + g) * NCHUNK];
        float4 v4a = *(const float4*)p;
        float4 v4b = *(const float4*)(p + 4);
        int lb = label[b * NGT + g];
        float cpr = 1.0f - prob[((size_t)(b * NQ + q)) * NCLS + lb];
        float s = ((v4a.x + v4a.y) + (v4a.z + v4a.w)) +
                  ((v4b.x + v4b.y) + (v4b.z + v4b.w));
        cost[g * 64 + q] = s + cpr;
    }
    __syncthreads();
    if (tid >= 64) return;            // wave 0 solves alone; no more barriers
    const int lane = tid;

    const float INF = __builtin_inff();
    float v = 0.f;        // dual for column `lane`
    float u_reg = 0.f;    // dual for row `lane` (valid lane<32)
    int c4r = -1;         // col4row for row `lane` (valid lane<32)
    int r4c = -1;         // row4col for column `lane`

    for (int cur = 0; cur < NGT; ++cur) {
        unsigned SRmask = 0;
        float shortest = INF;
        int pathv = 0;
        bool SC = false;
        float minVal = 0.f;
        int i = cur;
        int sink = -1;

        while (sink < 0) {
            SRmask |= (1u << i);
            float ci = cost[(i << 6) + lane];
            float ui = rdlane_f(u_reg, i);
            float lowest = minVal + ci - ui - v;
            if (!SC && lowest < shortest) { shortest = lowest; pathv = i; }
            float masked = SC ? INF : shortest;
            float x = masked;
            x = dppmin(x, 0xB1);    // xor 1
            x = dppmin(x, 0x4E);    // xor 2
            x = dppmin(x, 0x141);   // half-mirror -> min over 8
            x = dppmin(x, 0x140);   // mirror      -> min over 16
            float mv = rdlane_f(x, 0);
            mv = fminf(mv, rdlane_f(x, 16));
            mv = fminf(mv, rdlane_f(x, 32));
            mv = fminf(mv, rdlane_f(x, 48));
            unsigned long long ball = __ballot(masked == mv);
            int j = __ffsll(ball) - 1;          // first-index tie-break
            minVal = mv;
            if (lane == j) SC = true;
            int rr = __builtin_amdgcn_readlane(r4c, j);
            if (rr < 0) sink = j;
            else        i = rr;
        }

        // ---- dual updates (pre-augment col4row) ----
        if (lane == cur) u_reg += minVal;
        {
            float shc = __shfl(shortest, c4r & 63);
            bool rowupd = (lane < NGT) && (lane != cur) && ((SRmask >> lane) & 1u);
            if (rowupd) u_reg += minVal - shc;
        }
        if (SC) v -= minVal - shortest;

        // ---- augment back from sink ----
        int j = sink;
        while (true) {
            int ii = __builtin_amdgcn_readlane(pathv, j);
            if (lane == j) r4c = ii;
            int prev = __builtin_amdgcn_readlane(c4r, ii);
            if (lane == ii) c4r = j;
            if (ii == cur) break;
            j = prev;
        }
    }

    // ---- argsort(col4row) and write (rows, cols) ----
    int cc = c4r;
    int rank = 0;
    for (int t = 0; t < NGT; ++t) {
        int ct = __shfl(c4r, t);
        rank += (ct < cc) ? 1 : 0;
    }
    if (lane < NGT) {
        out[b * NGT + rank] = cc;                   // rows: matched query idx
        out[BS * NGT + b * NGT + rank] = lane;      // cols: corresponding gt idx
    }
}

extern "C" void kernel_launch(void* const* d_in, const int* in_sizes, int n_in,
                              void* d_out, int out_size, void* d_ws, size_t ws_size,
                              hipStream_t stream) {
    const float* prob  = (const float*)d_in[0];
    const int*   label = (const int*)d_in[1];
    const float* heat  = (const float*)d_in[2];
    const float* gt    = (const float*)d_in[3];
    int* out = (int*)d_out;
    float* Cp = (float*)d_ws;   // BS*NQ*NGT*NCHUNK floats = 1 MiB

    cost_kernel<<<dim3(BS * (NQ / QT) * NCHUNK), dim3(256), 0, stream>>>(heat, gt, Cp);
    // MEASUREMENT: lsap x3 (idempotent -> identical output). dur = C + 3L + ov.
    // L = (dur - 41.5)/2 - lambda; revert to single launch next round.
    lsap_kernel<<<dim3(BS), dim3(256), 0, stream>>>(Cp, prob, label, out);
    lsap_kernel<<<dim3(BS), dim3(256), 0, stream>>>(Cp, prob, label, out);
    lsap_kernel<<<dim3(BS), dim3(256), 0, stream>>>(Cp, prob, label, out);
}

// Round 8
// 37.481 us; speedup vs baseline: 2.3443x; 2.3443x over previous
//
#include <hip/hip_runtime.h>
#include <hip/hip_bf16.h>

// Problem constants (from setup_inputs): bs=16, nq=64, ngt=32, D=4096, ncls=33
#define BS   16
#define NQ   64
#define NGT  32
#define DIM  4096
#define NCLS 33

#define QT      8               // heat rows per block
#define NCHUNK  8               // D split
#define CHUNK   (DIM / NCHUNK)  // 512

// ---------------------------------------------------------------------------
// Kernel 1: partial cost  Cp[b][q][g][c] = sum_{d in chunk c} |heat[b,q,d]-gt[b,g,d]|
// (byte-identical to round 5)
// ---------------------------------------------------------------------------
__global__ __launch_bounds__(256) void cost_kernel(
    const float* __restrict__ heat, const float* __restrict__ gt,
    float* __restrict__ Cp)
{
    __shared__ float hrow[QT][CHUNK];   // 16 KB
    const int bid  = blockIdx.x;        // 16*8*8 = 1024 blocks
    const int b    = bid & 15;
    const int rest = bid >> 4;          // 0..63
    const int qt   = rest & (NQ / QT - 1);  // 0..7
    const int c    = rest >> 3;         // 0..7
    const int q0   = qt * QT;

    const float* hbase = heat + ((size_t)(b * NQ + q0)) * DIM + c * CHUNK;
    for (int i = threadIdx.x; i < QT * CHUNK / 4; i += 256) {
        int r = i >> 7;        // / (CHUNK/4 = 128)
        int k = i & 127;
        ((float4*)hrow[r])[k] = ((const float4*)(hbase + (size_t)r * DIM))[k];
    }
    __syncthreads();

    const int wave = threadIdx.x >> 6;
    const int lane = threadIdx.x & 63;
    const int g0 = wave * 8;
    const float* gbase = gt + ((size_t)(b * NGT + g0)) * DIM + c * CHUNK;

    float acc[8][QT];
    #pragma unroll
    for (int g = 0; g < 8; ++g)
        #pragma unroll
        for (int q = 0; q < QT; ++q) acc[g][q] = 0.f;

    for (int i = lane; i < CHUNK / 4; i += 64) {   // 2 iterations
        float4 hv[QT];
        #pragma unroll
        for (int q = 0; q < QT; ++q) hv[q] = ((float4*)hrow[q])[i];
        #pragma unroll
        for (int g = 0; g < 8; ++g) {
            float4 gv = ((const float4*)(gbase + (size_t)g * DIM))[i];
            #pragma unroll
            for (int q = 0; q < QT; ++q) {
                acc[g][q] += fabsf(hv[q].x - gv.x) + fabsf(hv[q].y - gv.y) +
                             fabsf(hv[q].z - gv.z) + fabsf(hv[q].w - gv.w);
            }
        }
    }

    // 64-value butterfly: after 6 stages lane l holds total of value index l
    float r[64];
    #pragma unroll
    for (int k = 0; k < 64; ++k) r[k] = acc[k >> 3][k & 7];
    #pragma unroll
    for (int n = 64, m = 1; n > 1; n >>= 1, m <<= 1) {
        #pragma unroll
        for (int k = 0; k < 32; ++k) {
            if (k < n / 2) {
                float a  = r[2 * k], bb = r[2 * k + 1];
                bool  hi = (lane & m) != 0;
                float keep = hi ? bb : a;
                float send = hi ? a : bb;
                r[k] = keep + __shfl_xor(send, m);
            }
        }
    }
    {
        int gl = lane >> 3, ql = lane & 7;
        Cp[(((size_t)(b * NQ + (q0 + ql))) * NGT + (g0 + gl)) * NCHUNK + c] = r[0];
    }
}

// ---------------------------------------------------------------------------
// Helpers.
// ---------------------------------------------------------------------------
template<int CTRL>
__device__ __forceinline__ float dppmin_t(float x) {
    // old = x, bound_ctrl = false: lanes without a valid DPP source keep x
    // (min(x,x) = x). Exact IEEE min; result is always one of the inputs.
    int t = __builtin_amdgcn_update_dpp(__float_as_int(x), __float_as_int(x),
                                        CTRL, 0xf, 0xf, false);
    return fminf(x, __int_as_float(t));
}
__device__ __forceinline__ float rdlane_f(float x, int l) {
    return __int_as_float(__builtin_amdgcn_readlane(__float_as_int(x), l));
}
// Exact min over all 64 lanes, returned wave-uniform (SGPR).
// 4 mirror stages (min within each row of 16) + row_bcast15/31 (cross-row)
// + one readlane(63).
__device__ __forceinline__ float wavemin64(float x) {
    x = dppmin_t<0xB1>(x);    // quad_perm xor1
    x = dppmin_t<0x4E>(x);    // quad_perm xor2
    x = dppmin_t<0x141>(x);   // row_half_mirror -> min over 8
    x = dppmin_t<0x140>(x);   // row_mirror      -> min over 16
    x = dppmin_t<0x142>(x);   // row_bcast15: lanes16-31=min(r0,r1), 48-63=min(r2,r3)
    x = dppmin_t<0x143>(x);   // row_bcast31: lanes48-63=min(all)
    return rdlane_f(x, 63);
}

// ---------------------------------------------------------------------------
// Kernel 2: exact rectangular LSAP (Jonker-Volgenant) with greedy dual
// initialization, one block per batch. All 4 waves stage cost[g][q] into LDS;
// wave 0 solves. Init: u[g] = min_q cost[g][q] (bit-exact wave-min), greedy
// match row g -> first argmin column if free (complementary slackness holds
// exactly: cost - u[g] - 0 == 0 on matched edges, reduced costs >= 0).
// Dijkstra then runs only for unmatched rows. Final assignment = the unique
// optimum = reference output.
// ---------------------------------------------------------------------------
__global__ __launch_bounds__(256) void lsap_kernel(
    const float* __restrict__ Cp, const float* __restrict__ prob,
    const int* __restrict__ label, int* __restrict__ out)
{
    __shared__ float cost[NGT * NQ];
    const int b = blockIdx.x;
    const int tid = threadIdx.x;

    // 2048 entries / 256 threads = 8 iterations; writes conflict-free.
    for (int idx = tid; idx < NQ * NGT; idx += 256) {
        int q = idx & 63;
        int g = idx >> 6;
        const float* p = &Cp[(((size_t)(b * NQ + q)) * NGT + g) * NCHUNK];
        float4 v4a = *(const float4*)p;
        float4 v4b = *(const float4*)(p + 4);
        int lb = label[b * NGT + g];
        float cpr = 1.0f - prob[((size_t)(b * NQ + q)) * NCLS + lb];
        float s = ((v4a.x + v4a.y) + (v4a.z + v4a.w)) +
                  ((v4b.x + v4b.y) + (v4b.z + v4b.w));
        cost[g * 64 + q] = s + cpr;
    }
    __syncthreads();
    if (tid >= 64) return;            // wave 0 solves alone; no more barriers
    const int lane = tid;

    const float INF = __builtin_inff();
    float v = 0.f;        // dual for column `lane`
    float u_reg = 0.f;    // dual for row `lane` (valid lane<32)
    int c4r = -1;         // col4row for row `lane` (valid lane<32)
    int r4c = -1;         // row4col for column `lane`

    // ---- greedy init: row mins + first-free-argmin matching ----
    {
        float xg[NGT]; float mg[NGT]; int jg[NGT];
        #pragma unroll
        for (int g = 0; g < NGT; ++g) xg[g] = cost[(g << 6) + lane];
        #pragma unroll
        for (int g = 0; g < NGT; ++g) {
            float m = wavemin64(xg[g]);
            unsigned long long ball = __ballot(xg[g] == m);
            jg[g] = __ffsll(ball) - 1;
            mg[g] = m;
        }
        #pragma unroll
        for (int g = 0; g < NGT; ++g) {
            int j = jg[g];
            int rtaken = __builtin_amdgcn_readlane(r4c, j);
            if (rtaken < 0) {
                if (lane == j) r4c = g;
                if (lane == g) c4r = j;
            }
            if (lane == g) u_reg = mg[g];
        }
    }

    for (int cur = 0; cur < NGT; ++cur) {
        if (__builtin_amdgcn_readlane(c4r, cur) >= 0) continue;  // greedy-matched

        unsigned SRmask = 0;
        float shortest = INF;
        int pathv = 0;
        bool SC = false;
        float minVal = 0.f;
        int i = cur;
        int sink = -1;

        while (sink < 0) {
            SRmask |= (1u << i);
            float ci = cost[(i << 6) + lane];
            float ui = rdlane_f(u_reg, i);
            float lowest = minVal + ci - ui - v;
            if (!SC && lowest < shortest) { shortest = lowest; pathv = i; }
            float masked = SC ? INF : shortest;
            float mv = wavemin64(masked);
            unsigned long long ball = __ballot(masked == mv);
            int j = __ffsll(ball) - 1;          // first-index tie-break
            minVal = mv;
            if (lane == j) SC = true;
            int rr = __builtin_amdgcn_readlane(r4c, j);
            if (rr < 0) sink = j;
            else        i = rr;
        }

        // ---- dual updates (pre-augment col4row) ----
        if (lane == cur) u_reg += minVal;
        {
            float shc = __shfl(shortest, c4r & 63);
            bool rowupd = (lane < NGT) && (lane != cur) && ((SRmask >> lane) & 1u);
            if (rowupd) u_reg += minVal - shc;
        }
        if (SC) v -= minVal - shortest;

        // ---- augment back from sink ----
        int j = sink;
        while (true) {
            int ii = __builtin_amdgcn_readlane(pathv, j);
            if (lane == j) r4c = ii;
            int prev = __builtin_amdgcn_readlane(c4r, ii);
            if (lane == ii) c4r = j;
            if (ii == cur) break;
            j = prev;
        }
    }

    // ---- argsort(col4row) and write (rows, cols) ----
    int cc = c4r;
    int rank = 0;
    for (int t = 0; t < NGT; ++t) {
        int ct = __shfl(c4r, t);
        rank += (ct < cc) ? 1 : 0;
    }
    if (lane < NGT) {
        out[b * NGT + rank] = cc;                   // rows: matched query idx
        out[BS * NGT + b * NGT + rank] = lane;      // cols: corresponding gt idx
    }
}

extern "C" void kernel_launch(void* const* d_in, const int* in_sizes, int n_in,
                              void* d_out, int out_size, void* d_ws, size_t ws_size,
                              hipStream_t stream) {
    const float* prob  = (const float*)d_in[0];
    const int*   label = (const int*)d_in[1];
    const float* heat  = (const float*)d_in[2];
    const float* gt    = (const float*)d_in[3];
    int* out = (int*)d_out;
    float* Cp = (float*)d_ws;   // BS*NQ*NGT*NCHUNK floats = 1 MiB

    cost_kernel<<<dim3(BS * (NQ / QT) * NCHUNK), dim3(256), 0, stream>>>(heat, gt, Cp);
    lsap_kernel<<<dim3(BS), dim3(256), 0, stream>>>(Cp, prob, label, out);
}